// Round 1
// baseline (544.844 us; speedup 1.0000x reference)
//
#include <hip/hip_runtime.h>
#include <hip/hip_bf16.h>
#include <stdint.h>

typedef float f32x4 __attribute__((ext_vector_type(4)));
typedef short bf16x8 __attribute__((ext_vector_type(8)));

#define NPATCH 6272      // 8*28*28
#define CTOT   384
#define MBANK  30000
#define MPAD   30080     // 235*128

// ---------------------------------------------------------------- prep: patches
// one wave per patch row: fused bilinear upsample of f3 + concat with f2,
// bf16 cast, x_sq (fp32), and nn_d2 = +inf init (ws is poisoned 0xAA = negative
// float, which would break the uint atomicMin ordering).
__global__ __launch_bounds__(256) void prep_patches_kernel(
    const float* __restrict__ f2, const float* __restrict__ f3,
    __hip_bfloat16* __restrict__ A, float* __restrict__ x_sq,
    float* __restrict__ nn_d2)
{
  const int lane = threadIdx.x & 63;
  const int n = blockIdx.x * 4 + (threadIdx.x >> 6);
  if (n >= NPATCH) return;
  const int b = n / 784;
  const int hw = n - b * 784;
  const int h = hw / 28;
  const int w = hw - h * 28;

  // align_corners=False bilinear, scale 2: src = out/2 - 0.25; edge-clamp ==
  // jax's weight renormalization at borders.
  int h0, h1, w0i, w1i; float wh0, wh1, ww0, ww1;
  if (h & 1) { int k = h >> 1; h0 = k; h1 = (k + 1 < 14) ? k + 1 : 13; wh0 = 0.75f; wh1 = 0.25f; }
  else       { int k = h >> 1; h0 = (k > 0) ? k - 1 : 0; h1 = k;       wh0 = 0.25f; wh1 = 0.75f; }
  if (w & 1) { int k = w >> 1; w0i = k; w1i = (k + 1 < 14) ? k + 1 : 13; ww0 = 0.75f; ww1 = 0.25f; }
  else       { int k = w >> 1; w0i = (k > 0) ? k - 1 : 0; w1i = k;       ww0 = 0.25f; ww1 = 0.75f; }

  float ssum = 0.f;
  #pragma unroll
  for (int j = 0; j < 6; ++j) {
    const int c = j * 64 + lane;
    float v;
    if (j < 2) {
      v = f2[(((size_t)b * 128 + c) * 28 + h) * 28 + w];
    } else {
      const int c3 = c - 128;
      const float* p = f3 + ((size_t)b * 256 + c3) * 196;
      v = wh0 * (ww0 * p[h0 * 14 + w0i] + ww1 * p[h0 * 14 + w1i]) +
          wh1 * (ww0 * p[h1 * 14 + w0i] + ww1 * p[h1 * 14 + w1i]);
    }
    A[(size_t)n * CTOT + c] = __float2bfloat16(v);
    ssum += v * v;
  }
  #pragma unroll
  for (int off = 32; off; off >>= 1) ssum += __shfl_xor(ssum, off);
  if (lane == 0) { x_sq[n] = ssum; nn_d2[n] = __uint_as_float(0x7f800000u); }
}

// ---------------------------------------------------------------- prep: bank
__global__ __launch_bounds__(256) void prep_bank_kernel(
    const float* __restrict__ mb, __hip_bfloat16* __restrict__ Bb,
    float* __restrict__ m_sq)
{
  const int lane = threadIdx.x & 63;
  const int m = blockIdx.x * 4 + (threadIdx.x >> 6);
  if (m >= MPAD) return;
  if (m < MBANK) {
    float ssum = 0.f;
    #pragma unroll
    for (int j = 0; j < 6; ++j) {
      const int c = j * 64 + lane;
      const float v = mb[(size_t)m * CTOT + c];
      Bb[(size_t)m * CTOT + c] = __float2bfloat16(v);
      ssum += v * v;
    }
    #pragma unroll
    for (int off = 32; off; off >>= 1) ssum += __shfl_xor(ssum, off);
    if (lane == 0) m_sq[m] = ssum;
  } else {
    // padded rows: dot = 0, m_sq = +inf -> never the min
    #pragma unroll
    for (int j = 0; j < 6; ++j) Bb[(size_t)m * CTOT + j * 64 + lane] = __float2bfloat16(0.f);
    if (lane == 0) m_sq[m] = __uint_as_float(0x7f800000u);
  }
}

// ---------------------------------------------------------------- GEMM + row-min
__device__ __forceinline__ void gl_lds16(const void* g, void* l) {
  __builtin_amdgcn_global_load_lds(
      (const __attribute__((address_space(1))) uint32_t*)g,
      (__attribute__((address_space(3))) uint32_t*)l, 16, 0, 0);
}

// 128x128 tile, BK=64, 4 waves (2x2, each 64x64 = 4x4 frags of 16x16x32 bf16).
// Epilogue: per-row min of (m_sq[col] - 2*acc) via 16-lane shfl, + x_sq[row],
// clamped >=0, then device atomicMin on the uint bit pattern (valid for >=0).
__global__ __launch_bounds__(256) void gemm_min_kernel(
    const __hip_bfloat16* __restrict__ A, const __hip_bfloat16* __restrict__ B,
    const float* __restrict__ x_sq, const float* __restrict__ m_sq,
    float* __restrict__ nn_d2)
{
  __shared__ __align__(16) short As[128 * 64];
  __shared__ __align__(16) short Bs[128 * 64];
  const int tid  = threadIdx.x;
  const int lane = tid & 63;
  const int wid  = tid >> 6;
  const int wr = wid >> 1, wc = wid & 1;
  const int row0 = blockIdx.y * 128;   // patch rows
  const int col0 = blockIdx.x * 128;   // bank cols

  f32x4 acc[4][4];
  #pragma unroll
  for (int i = 0; i < 4; ++i)
    #pragma unroll
    for (int j = 0; j < 4; ++j) acc[i][j] = (f32x4){0.f, 0.f, 0.f, 0.f};

  for (int kt = 0; kt < 6; ++kt) {
    const int k0 = kt * 64;
    // stage 128x64 bf16 each of A,B: 1024 16B chunks per tile, 4/thread.
    #pragma unroll
    for (int j = 0; j < 4; ++j) {
      const int cbase = wid * 256 + j * 64;  // wave-uniform LDS chunk base
      const int chunk = cbase + lane;
      const int r  = chunk >> 3;
      const int kc = (chunk & 7) << 3;
      gl_lds16(A + (size_t)(row0 + r) * CTOT + (k0 + kc), &As[cbase * 8]);
      gl_lds16(B + (size_t)(col0 + r) * CTOT + (k0 + kc), &Bs[cbase * 8]);
    }
    __syncthreads();   // compiler drains vmcnt before s_barrier
    #pragma unroll
    for (int kk = 0; kk < 2; ++kk) {
      const int kl = kk * 32 + (lane >> 4) * 8;
      bf16x8 af[4], bfv[4];
      #pragma unroll
      for (int mi = 0; mi < 4; ++mi)
        af[mi] = *(const bf16x8*)&As[(wr * 64 + mi * 16 + (lane & 15)) * 64 + kl];
      #pragma unroll
      for (int ni = 0; ni < 4; ++ni)
        bfv[ni] = *(const bf16x8*)&Bs[(wc * 64 + ni * 16 + (lane & 15)) * 64 + kl];
      #pragma unroll
      for (int mi = 0; mi < 4; ++mi)
        #pragma unroll
        for (int ni = 0; ni < 4; ++ni)
          acc[mi][ni] = __builtin_amdgcn_mfma_f32_16x16x32_bf16(af[mi], bfv[ni], acc[mi][ni], 0, 0, 0);
    }
    __syncthreads();
  }

  // epilogue: C/D layout col=lane&15, row=(lane>>4)*4+reg  [m89-verified]
  float msq[4];
  #pragma unroll
  for (int ni = 0; ni < 4; ++ni) msq[ni] = m_sq[col0 + wc * 64 + ni * 16 + (lane & 15)];

  #pragma unroll
  for (int mi = 0; mi < 4; ++mi) {
    #pragma unroll
    for (int r = 0; r < 4; ++r) {
      float t = msq[0] - 2.f * acc[mi][0][r];
      #pragma unroll
      for (int ni = 1; ni < 4; ++ni) t = fminf(t, msq[ni] - 2.f * acc[mi][ni][r]);
      t = fminf(t, __shfl_xor(t, 1));
      t = fminf(t, __shfl_xor(t, 2));
      t = fminf(t, __shfl_xor(t, 4));
      t = fminf(t, __shfl_xor(t, 8));
      if ((lane & 15) == 0) {
        const int rg = row0 + wr * 64 + mi * 16 + ((lane >> 4) << 2) + r;
        const float v = fmaxf(t + x_sq[rg], 0.f);
        atomicMin((unsigned int*)&nn_d2[rg], __float_as_uint(v));
      }
    }
  }
}

// ---------------------------------------------------------------- finalize
__global__ __launch_bounds__(256) void finalize_kernel(
    const float* __restrict__ nn_d2, float* __restrict__ out)
{
  const int b = blockIdx.x;
  const int tid = threadIdx.x;
  __shared__ float red[4];
  float lmax = 0.f;
  for (int i = tid; i < 784; i += 256) {
    const float d2 = nn_d2[b * 784 + i];
    const float s = sqrtf(fmaxf(d2, 1e-12f));
    out[b * 784 + i] = s;
    lmax = fmaxf(lmax, s);
  }
  #pragma unroll
  for (int off = 32; off; off >>= 1) lmax = fmaxf(lmax, __shfl_xor(lmax, off));
  if ((tid & 63) == 0) red[tid >> 6] = lmax;
  __syncthreads();
  if (tid == 0)
    out[6272 + b] = fmaxf(fmaxf(red[0], red[1]), fmaxf(red[2], red[3]));
}

// ---------------------------------------------------------------- launch
extern "C" void kernel_launch(void* const* d_in, const int* in_sizes, int n_in,
                              void* d_out, int out_size, void* d_ws, size_t ws_size,
                              hipStream_t stream)
{
  const float* f2 = (const float*)d_in[0];   // [8,128,28,28]
  const float* f3 = (const float*)d_in[1];   // [8,256,14,14]
  const float* mb = (const float*)d_in[2];   // [30000,384]
  float* out = (float*)d_out;                // 6272 patch scores + 8 img scores

  // workspace layout (bytes), total ~28.1 MB
  uint8_t* ws = (uint8_t*)d_ws;
  __hip_bfloat16* A  = (__hip_bfloat16*)(ws);              // 6272*384*2  = 4,816,896
  __hip_bfloat16* Bb = (__hip_bfloat16*)(ws + 4816896);    // 30080*384*2 = 23,101,440
  float* x_sq  = (float*)(ws + 27918336);                  // 6272*4
  float* m_sq  = (float*)(ws + 27943424);                  // 30080*4
  float* nn_d2 = (float*)(ws + 28063744);                  // 6272*4

  hipLaunchKernelGGL(prep_patches_kernel, dim3(NPATCH / 4), dim3(256), 0, stream,
                     f2, f3, A, x_sq, nn_d2);
  hipLaunchKernelGGL(prep_bank_kernel, dim3(MPAD / 4), dim3(256), 0, stream,
                     mb, Bb, m_sq);
  hipLaunchKernelGGL(gemm_min_kernel, dim3(MPAD / 128, NPATCH / 128), dim3(256), 0, stream,
                     A, Bb, x_sq, m_sq, nn_d2);
  hipLaunchKernelGGL(finalize_kernel, dim3(8), dim3(256), 0, stream, nn_d2, out);
}

// Round 2
// 452.473 us; speedup vs baseline: 1.2041x; 1.2041x over previous
//
#include <hip/hip_runtime.h>
#include <hip/hip_bf16.h>
#include <stdint.h>

typedef float f32x4 __attribute__((ext_vector_type(4)));
typedef short bf16x8 __attribute__((ext_vector_type(8)));

#define NPATCH 6272      // 8*28*28
#define CTOT   384
#define MBANK  30000
#define MROWS  6400      // NPATCH padded to 25*256
#define NCOLS  30208     // MBANK padded to 118*256
#define NKT    6         // 384/64 K-tiles

// ---------------------------------------------------------------- prep: patches
__global__ __launch_bounds__(256) void prep_patches_kernel(
    const float* __restrict__ f2, const float* __restrict__ f3,
    __hip_bfloat16* __restrict__ A, float* __restrict__ x_sq,
    float* __restrict__ nn_d2)
{
  const int lane = threadIdx.x & 63;
  const int n = blockIdx.x * 4 + (threadIdx.x >> 6);
  if (n >= MROWS) return;
  if (n >= NPATCH) {       // zero-fill pad rows (deterministic staging)
    #pragma unroll
    for (int j = 0; j < 6; ++j) A[(size_t)n * CTOT + j * 64 + lane] = __float2bfloat16(0.f);
    return;
  }
  const int b = n / 784;
  const int hw = n - b * 784;
  const int h = hw / 28;
  const int w = hw - h * 28;

  // align_corners=False bilinear, scale 2 (edge-clamped == jax renormalized)
  int h0, h1, w0i, w1i; float wh0, wh1, ww0, ww1;
  if (h & 1) { int k = h >> 1; h0 = k; h1 = (k + 1 < 14) ? k + 1 : 13; wh0 = 0.75f; wh1 = 0.25f; }
  else       { int k = h >> 1; h0 = (k > 0) ? k - 1 : 0; h1 = k;       wh0 = 0.25f; wh1 = 0.75f; }
  if (w & 1) { int k = w >> 1; w0i = k; w1i = (k + 1 < 14) ? k + 1 : 13; ww0 = 0.75f; ww1 = 0.25f; }
  else       { int k = w >> 1; w0i = (k > 0) ? k - 1 : 0; w1i = k;       ww0 = 0.25f; ww1 = 0.75f; }

  float ssum = 0.f;
  #pragma unroll
  for (int j = 0; j < 6; ++j) {
    const int c = j * 64 + lane;
    float v;
    if (j < 2) {
      v = f2[(((size_t)b * 128 + c) * 28 + h) * 28 + w];
    } else {
      const int c3 = c - 128;
      const float* p = f3 + ((size_t)b * 256 + c3) * 196;
      v = wh0 * (ww0 * p[h0 * 14 + w0i] + ww1 * p[h0 * 14 + w1i]) +
          wh1 * (ww0 * p[h1 * 14 + w0i] + ww1 * p[h1 * 14 + w1i]);
    }
    A[(size_t)n * CTOT + c] = __float2bfloat16(v);
    ssum += v * v;
  }
  #pragma unroll
  for (int off = 32; off; off >>= 1) ssum += __shfl_xor(ssum, off);
  if (lane == 0) { x_sq[n] = ssum; nn_d2[n] = __uint_as_float(0x7f800000u); }
}

// ---------------------------------------------------------------- prep: bank
__global__ __launch_bounds__(256) void prep_bank_kernel(
    const float* __restrict__ mb, __hip_bfloat16* __restrict__ Bb,
    float* __restrict__ m_sq)
{
  const int lane = threadIdx.x & 63;
  const int m = blockIdx.x * 4 + (threadIdx.x >> 6);
  if (m >= NCOLS) return;
  if (m < MBANK) {
    float ssum = 0.f;
    #pragma unroll
    for (int j = 0; j < 3; ++j) {
      const int c = j * 128 + lane * 2;
      const float2 v = *(const float2*)&mb[(size_t)m * CTOT + c];
      short2 o;
      o.x = (short)__bfloat16_as_ushort(__float2bfloat16(v.x));
      o.y = (short)__bfloat16_as_ushort(__float2bfloat16(v.y));
      *(short2*)&Bb[(size_t)m * CTOT + c] = o;
      ssum += v.x * v.x + v.y * v.y;
    }
    #pragma unroll
    for (int off = 32; off; off >>= 1) ssum += __shfl_xor(ssum, off);
    if (lane == 0) m_sq[m] = ssum;
  } else {
    #pragma unroll
    for (int j = 0; j < 6; ++j) Bb[(size_t)m * CTOT + j * 64 + lane] = __float2bfloat16(0.f);
    if (lane == 0) m_sq[m] = __uint_as_float(0x7f800000u);
  }
}

// ---------------------------------------------------------------- GEMM + row-min
__device__ __forceinline__ void gl_lds16(const void* g, void* l) {
  __builtin_amdgcn_global_load_lds(
      (const __attribute__((address_space(1))) uint32_t*)g,
      (__attribute__((address_space(3))) uint32_t*)l, 16, 0, 0);
}

// 256x256 tile, BK=64, 8 waves (2Mx4N; 128x64 per wave, 8x4 frags of 16x16x32).
// Double-buffered 128KB LDS, raw s_barrier + counted vmcnt(8) (loads stay in
// flight across barriers), 16B-chunk XOR swizzle (chunk ^= row&7) applied as
// inverse-swizzled GLOBAL source + swizzled ds_read addr (linear gl_lds dest).
__global__ __launch_bounds__(512, 2) void gemm_min_kernel(
    const __hip_bfloat16* __restrict__ A, const __hip_bfloat16* __restrict__ B,
    const float* __restrict__ x_sq, const float* __restrict__ m_sq,
    float* __restrict__ nn_d2)
{
  __shared__ __align__(16) short As[2][256 * 64];
  __shared__ __align__(16) short Bs[2][256 * 64];
  const int tid  = threadIdx.x;
  const int lane = tid & 63;
  const int wid  = tid >> 6;
  const int wr = wid >> 2;          // 0..1  (M half)
  const int wc = wid & 3;           // 0..3  (N quarter)
  const int row0 = blockIdx.y * 256;
  const int col0 = blockIdx.x * 256;

  f32x4 acc[8][4];
  #pragma unroll
  for (int i = 0; i < 8; ++i)
    #pragma unroll
    for (int j = 0; j < 4; ++j) acc[i][j] = (f32x4){0.f, 0.f, 0.f, 0.f};

  // stage one K-tile (A+B, 32KB each) into buffer `buf`: 8 loads/thread.
  // LDS dest linear; global source chunk pre-swizzled (ch ^= row&7).
  auto stage = [&](int kt, int buf) {
    const int k0 = kt * 64;
    #pragma unroll
    for (int j = 0; j < 4; ++j) {
      const int cb = j * 512 + wid * 64;      // wave-uniform chunk base
      const int c  = cb + lane;
      const int r  = c >> 3;                  // tile row 0..255
      const int ch = (c & 7) ^ (r & 7);       // swizzled 16B chunk in row
      gl_lds16(A + (size_t)(row0 + r) * CTOT + k0 + ch * 8, &As[buf][cb * 8]);
      gl_lds16(B + (size_t)(col0 + r) * CTOT + k0 + ch * 8, &Bs[buf][cb * 8]);
    }
  };

  stage(0, 0);
  stage(1, 1);
  asm volatile("s_waitcnt vmcnt(8)" ::: "memory");   // tile 0 landed
  __builtin_amdgcn_s_barrier();

  const int sw = lane & 7;            // row&7 for all this lane's frag rows
  const int rA = wr * 128 + (lane & 15);
  const int rB = wc * 64 + (lane & 15);
  const int kq = lane >> 4;           // k-quarter 0..3

  #pragma unroll
  for (int t = 0; t < NKT; ++t) {
    const int cur = t & 1;
    const short* lA = As[cur];
    const short* lB = Bs[cur];
    const int ch0 = (kq ^ sw) << 4;         // kk=0 swizzled byte chunk
    const int ch1 = ((4 + kq) ^ sw) << 4;   // kk=1

    bf16x8 a0[8], b0[4], a1[8], b1[4];
    #pragma unroll
    for (int mi = 0; mi < 8; ++mi)
      a0[mi] = *(const bf16x8*)((const char*)lA + (rA + mi * 16) * 128 + ch0);
    #pragma unroll
    for (int ni = 0; ni < 4; ++ni)
      b0[ni] = *(const bf16x8*)((const char*)lB + (rB + ni * 16) * 128 + ch0);
    #pragma unroll
    for (int mi = 0; mi < 8; ++mi)
      a1[mi] = *(const bf16x8*)((const char*)lA + (rA + mi * 16) * 128 + ch1);
    #pragma unroll
    for (int ni = 0; ni < 4; ++ni)
      b1[ni] = *(const bf16x8*)((const char*)lB + (rB + ni * 16) * 128 + ch1);

    // kk=0 MFMAs (overlap with kk=1 ds_reads still in flight)
    #pragma unroll
    for (int mi = 0; mi < 8; ++mi)
      #pragma unroll
      for (int ni = 0; ni < 4; ++ni)
        acc[mi][ni] = __builtin_amdgcn_mfma_f32_16x16x32_bf16(a0[mi], b0[ni], acc[mi][ni], 0, 0, 0);

    // all my ds_reads of buf[cur] done -> after barrier it's safe to overwrite
    asm volatile("s_waitcnt lgkmcnt(0)" ::: "memory");
    __builtin_amdgcn_s_barrier();
    if (t + 2 < NKT) stage(t + 2, cur);

    __builtin_amdgcn_s_setprio(1);
    #pragma unroll
    for (int mi = 0; mi < 8; ++mi)
      #pragma unroll
      for (int ni = 0; ni < 4; ++ni)
        acc[mi][ni] = __builtin_amdgcn_mfma_f32_16x16x32_bf16(a1[mi], b1[ni], acc[mi][ni], 0, 0, 0);
    __builtin_amdgcn_s_setprio(0);

    if (t + 2 < NKT) {
      asm volatile("s_waitcnt vmcnt(8)" ::: "memory");  // tile t+1 landed, t+2 in flight
    } else {
      asm volatile("s_waitcnt vmcnt(0)" ::: "memory");  // tail: drain
    }
    __builtin_amdgcn_s_barrier();
  }

  // epilogue: C/D frag layout col=lane&15, row=(lane>>4)*4+reg
  float msq[4];
  #pragma unroll
  for (int ni = 0; ni < 4; ++ni) msq[ni] = m_sq[col0 + wc * 64 + ni * 16 + (lane & 15)];

  #pragma unroll
  for (int mi = 0; mi < 8; ++mi) {
    #pragma unroll
    for (int r = 0; r < 4; ++r) {
      float t = msq[0] - 2.f * acc[mi][0][r];
      #pragma unroll
      for (int ni = 1; ni < 4; ++ni) t = fminf(t, msq[ni] - 2.f * acc[mi][ni][r]);
      t = fminf(t, __shfl_xor(t, 1));
      t = fminf(t, __shfl_xor(t, 2));
      t = fminf(t, __shfl_xor(t, 4));
      t = fminf(t, __shfl_xor(t, 8));
      if ((lane & 15) == 0) {
        const int rg = row0 + wr * 128 + mi * 16 + ((lane >> 4) << 2) + r;
        if (rg < NPATCH) {
          const float v = fmaxf(t + x_sq[rg], 0.f);
          atomicMin((unsigned int*)&nn_d2[rg], __float_as_uint(v));
        }
      }
    }
  }
}

// ---------------------------------------------------------------- finalize
__global__ __launch_bounds__(256) void finalize_kernel(
    const float* __restrict__ nn_d2, float* __restrict__ out)
{
  const int b = blockIdx.x;
  const int tid = threadIdx.x;
  __shared__ float red[4];
  float lmax = 0.f;
  for (int i = tid; i < 784; i += 256) {
    const float d2 = nn_d2[b * 784 + i];
    const float s = sqrtf(fmaxf(d2, 1e-12f));
    out[b * 784 + i] = s;
    lmax = fmaxf(lmax, s);
  }
  #pragma unroll
  for (int off = 32; off; off >>= 1) lmax = fmaxf(lmax, __shfl_xor(lmax, off));
  if ((tid & 63) == 0) red[tid >> 6] = lmax;
  __syncthreads();
  if (tid == 0)
    out[6272 + b] = fmaxf(fmaxf(red[0], red[1]), fmaxf(red[2], red[3]));
}

// ---------------------------------------------------------------- launch
extern "C" void kernel_launch(void* const* d_in, const int* in_sizes, int n_in,
                              void* d_out, int out_size, void* d_ws, size_t ws_size,
                              hipStream_t stream)
{
  const float* f2 = (const float*)d_in[0];   // [8,128,28,28]
  const float* f3 = (const float*)d_in[1];   // [8,256,14,14]
  const float* mb = (const float*)d_in[2];   // [30000,384]
  float* out = (float*)d_out;                // 6272 patch scores + 8 img scores

  // workspace layout (16B-aligned offsets), total ~28.3 MB
  uint8_t* ws = (uint8_t*)d_ws;
  __hip_bfloat16* A  = (__hip_bfloat16*)(ws);              // 6400*384*2  = 4,915,200
  __hip_bfloat16* Bb = (__hip_bfloat16*)(ws + 4915200);    // 30208*384*2 = 23,199,744
  float* x_sq  = (float*)(ws + 28114944);                  // 6400*4
  float* m_sq  = (float*)(ws + 28140544);                  // 30208*4
  float* nn_d2 = (float*)(ws + 28261376);                  // 6272*4

  hipLaunchKernelGGL(prep_patches_kernel, dim3(MROWS / 4), dim3(256), 0, stream,
                     f2, f3, A, x_sq, nn_d2);
  hipLaunchKernelGGL(prep_bank_kernel, dim3(NCOLS / 4), dim3(256), 0, stream,
                     mb, Bb, m_sq);
  hipLaunchKernelGGL(gemm_min_kernel, dim3(NCOLS / 256, MROWS / 256), dim3(512), 0, stream,
                     A, Bb, x_sq, m_sq, nn_d2);
  hipLaunchKernelGGL(finalize_kernel, dim3(8), dim3(256), 0, stream, nn_d2, out);
}